// Round 8
// baseline (109.697 us; speedup 1.0000x reference)
//
#include <hip/hip_runtime.h>

// TreeCRF inside pass, L=32 channels, perfect binary tree (heap layout).
// parent[i] = em[i] + LSE_j(T[i,j]+left[j]) + LSE_j(T[i,j]+right[j])
// LSE_j(T[i,j]+c[j]) = m + log(sum_j E[i,j]*exp(c[j]-m)), E=exp(T), m=max_j c[j].
//
// R8: single fused kernel. 512 blocks x 512 thr each run an 8-level subtree
// (256 leaves -> 1 row of the width-512 level) via the R7 MFMA formulation
// (Y = E * C^T with mfma_f32_16x16x32_bf16; exp-child rows as bf16 B-frags in
// LDS; D layout col=lane&15=child, row=(lane>>4)*4+reg). Then last-block-done:
// __threadfence + atomicAdd ticket; ticket 511 (all other blocks' out512
// writes release-visible, no spinning -> XCD-coherence-safe) runs the 9-level
// top tree to the root in the same kernel. Counter zeroed by a hipMemsetAsync
// graph node (d_ws is poisoned 0xAA before every launch).

typedef float f32x4 __attribute__((ext_vector_type(4)));
typedef short s16x8 __attribute__((ext_vector_type(8)));
typedef short s16x4 __attribute__((ext_vector_type(4)));

__device__ __forceinline__ short f2bf(float f) {
    unsigned u = __builtin_bit_cast(unsigned, f);
    unsigned r = (u + 0x7fffu + ((u >> 16) & 1u)) >> 16;   // RNE to bf16
    return (short)r;
}

#define MSTEP(mask) { float4 o; o.x=__shfl_xor(r.x,mask); o.y=__shfl_xor(r.y,mask); \
                      o.z=__shfl_xor(r.z,mask); o.w=__shfl_xor(r.w,mask); \
                      r.x=fmaxf(r.x,o.x); r.y=fmaxf(r.y,o.y); \
                      r.z=fmaxf(r.z,o.z); r.w=fmaxf(r.w,o.w); }

template <int NT, int LEVELS>
__device__ __forceinline__ void run_tree(
    const int t, int Wp, int boff, const int b,
    const float* __restrict__ gchild,   // [2^LEVELS][32] first-level rows (f32)
    const float* __restrict__ em,
    const s16x8 a0, const s16x8 a1,     // E bf16 A-fragments (i 0..15 / 16..31)
    short* __restrict__ CA, float* __restrict__ MA,
    short* __restrict__ CB, float* __restrict__ MB,
    float* __restrict__ gout)           // [32]
{
    const int NC0 = 1 << LEVELS;
    // stage 0: global rows -> (max, exp row bf16) in CA/MA. 8 lanes per row.
    for (int u = t; u < NC0 * 8; u += NT) {
        int ql = u >> 3, k = u & 7;
        float4 x = ((const float4*)(gchild + (size_t)ql * 32))[k];
        float4 r = x;
        MSTEP(1) MSTEP(2) MSTEP(4)
        float m = fmaxf(fmaxf(r.x, r.y), fmaxf(r.z, r.w));
        s16x4 w;
        w[0] = f2bf(__expf(x.x - m)); w[1] = f2bf(__expf(x.y - m));
        w[2] = f2bf(__expf(x.z - m)); w[3] = f2bf(__expf(x.w - m));
        *((s16x4*)(CA + ql * 32 + k * 4)) = w;
        if (k == 0) MA[ql] = m;
    }
    __syncthreads();

    short* Cs = CA; float* Ms = MA;
    short* Cd = CB; float* Md = MB;
    const int lane = t & 63, wv = t >> 6, nw = NT / 64;
    const int ql = lane & 15, kg = lane >> 4;
    int nc = NC0;
    for (int l = 0; l < LEVELS; ++l) {
        int nqt = (nc >= 16) ? (nc >> 4) : 1;
        for (int qt = wv; qt < nqt; qt += nw) {
            int q = qt * 16 + ql;
            bool valid = q < nc;
            s16x8 bf = *((const s16x8*)(Cs + q * 32 + kg * 8));
            f32x4 d0 = {0.f, 0.f, 0.f, 0.f};
            f32x4 d1 = {0.f, 0.f, 0.f, 0.f};
            d0 = __builtin_amdgcn_mfma_f32_16x16x32_bf16(a0, bf, d0, 0, 0, 0);
            d1 = __builtin_amdgcn_mfma_f32_16x16x32_bf16(a1, bf, d1, 0, 0, 0);
            float mq = Ms[q];
            int p = qt * 8 + (ql >> 1);
            size_t node = (size_t)(Wp - 1) + (size_t)boff * b + p;
            const float4 e0 = *((const float4*)(em + node * 32 + kg * 4));
            const float4 e1 = *((const float4*)(em + node * 32 + 16 + kg * 4));
            float v0[4], v1[4];
#pragma unroll
            for (int r2 = 0; r2 < 4; ++r2) {
                float t0 = mq + __logf(d0[r2]);
                float t1 = mq + __logf(d1[r2]);
                v0[r2] = t0 + __shfl_xor(t0, 1);   // + sibling child (q^1)
                v1[r2] = t1 + __shfl_xor(t1, 1);
            }
            v0[0] += e0.x; v0[1] += e0.y; v0[2] += e0.z; v0[3] += e0.w;
            v1[0] += e1.x; v1[1] += e1.y; v1[2] += e1.z; v1[3] += e1.w;
            if (l == LEVELS - 1) {
                if (ql == 0) {                     // one parent: write 32 floats
                    float4 o0 = {v0[0], v0[1], v0[2], v0[3]};
                    float4 o1 = {v1[0], v1[1], v1[2], v1[3]};
                    *((float4*)(gout + kg * 4)) = o0;
                    *((float4*)(gout + 16 + kg * 4)) = o1;
                }
            } else {
                float m2 = fmaxf(fmaxf(fmaxf(v0[0], v0[1]), fmaxf(v0[2], v0[3])),
                                 fmaxf(fmaxf(v1[0], v1[1]), fmaxf(v1[2], v1[3])));
                m2 = fmaxf(m2, __shfl_xor(m2, 16));
                m2 = fmaxf(m2, __shfl_xor(m2, 32));  // max over all 32 rows i
                if (valid && !(ql & 1)) {
                    s16x4 w0, w1;
                    w0[0] = f2bf(__expf(v0[0] - m2)); w0[1] = f2bf(__expf(v0[1] - m2));
                    w0[2] = f2bf(__expf(v0[2] - m2)); w0[3] = f2bf(__expf(v0[3] - m2));
                    w1[0] = f2bf(__expf(v1[0] - m2)); w1[1] = f2bf(__expf(v1[1] - m2));
                    w1[2] = f2bf(__expf(v1[2] - m2)); w1[3] = f2bf(__expf(v1[3] - m2));
                    *((s16x4*)(Cd + p * 32 + kg * 4)) = w0;
                    *((s16x4*)(Cd + p * 32 + 16 + kg * 4)) = w1;
                    if (kg == 0) Md[p] = m2;
                }
            }
        }
        __syncthreads();
        short* tc = Cs; Cs = Cd; Cd = tc;
        float* tm = Ms; Ms = Md; Md = tm;
        nc >>= 1; Wp >>= 1; boff >>= 1;
    }
}

__device__ __forceinline__ void load_afrag(const float* __restrict__ trans,
                                           int row, int kg, s16x8* a)
{
#pragma unroll
    for (int j = 0; j < 8; ++j)
        (*a)[j] = f2bf(__expf(trans[row * 32 + kg * 8 + j]));
}

// Fused: 512 blocks x 512 thr. Bottom 8 levels each; ticket-511 block then
// runs the 9-level top tree (512 rows -> root).
__global__ __launch_bounds__(512) void treecrf_fused(
    const float* __restrict__ em, const float* __restrict__ trans,
    float* __restrict__ out512, int* __restrict__ counter,
    float* __restrict__ out_root, int n_leaves, int nbm1)
{
    __shared__ short CA[512 * 32];     // 32 KB (top needs 512 rows)
    __shared__ short CB[256 * 32];     // 16 KB
    __shared__ float MA[512];
    __shared__ float MB[256];
    __shared__ int last_flag;
    int t = threadIdx.x, b = blockIdx.x;
    int ql = t & 15, kg = (t & 63) >> 4;
    s16x8 a0, a1;
    load_afrag(trans, ql, kg, &a0);
    load_afrag(trans, ql + 16, kg, &a1);

    run_tree<512, 8>(t, n_leaves >> 1, 128, b,
                     em + (size_t)(n_leaves - 1 + 256 * b) * 32, em, a0, a1,
                     CA, MA, CB, MB, out512 + (size_t)b * 32);

    if (t == 0) {
        __threadfence();                       // release out512 row
        last_flag = (atomicAdd(counter, 1) == nbm1);
    }
    __syncthreads();
    if (!last_flag) return;
    __threadfence();                           // acquire all out512 rows

    run_tree<512, 9>(t, 256, 0, 0, out512, em, a0, a1,
                     CA, MA, CB, MB, out_root);
}

extern "C" void kernel_launch(void* const* d_in, const int* in_sizes, int n_in,
                              void* d_out, int out_size, void* d_ws, size_t ws_size,
                              hipStream_t stream)
{
    const float* em = (const float*)d_in[0];
    const float* trans = (const float*)d_in[1];
    int n_nodes = in_sizes[0] / 32;          // 262143
    int n_leaves = (n_nodes + 1) / 2;        // 131072
    int blocks = n_leaves / 256;             // 512

    float* out512 = (float*)d_ws;            // 512*32 floats = 64 KB
    int* counter = (int*)((char*)d_ws + 512 * 32 * sizeof(float));

    hipMemsetAsync(counter, 0, sizeof(int), stream);   // graph memset node
    treecrf_fused<<<dim3(blocks), dim3(512), 0, stream>>>(
        em, trans, out512, counter, (float*)d_out, n_leaves, blocks - 1);
}

// Round 9
// 98.042 us; speedup vs baseline: 1.1189x; 1.1189x over previous
//
#include <hip/hip_runtime.h>

// TreeCRF inside pass, L=32 channels, perfect binary tree (heap layout).
// parent[i] = em[i] + LSE_j(T[i,j]+left[j]) + LSE_j(T[i,j]+right[j])
// LSE_j(T[i,j]+c[j]) = m + log(sum_j E[i,j]*exp(c[j]-m)), E=exp(T), m=max_j c[j].
//
// R9: wave-autonomous subtrees. One wave reduces a 32-row subtree to 1 row
// with NO cross-wave coupling: per level, Y = E*C^T via one 16x16x32 bf16
// MFMA stripe pair (B-frags read from wave-private LDS rows, stride 40
// shorts = conflict-free), epilogue = log + sibling shfl_xor(1) + em add +
// row-max shfl butterfly + exp -> bf16 parent row. Latency hidden by many
// independent waves (TLP), not barriers.
// K1: 4096 waves (131072 leaves -> 4096), K2: 128 waves (4096 -> 128),
// K3: 1 block (4 waves 128 -> 4 in LDS, then wave 0 does 4 -> 1).

typedef float f32x4 __attribute__((ext_vector_type(4)));
typedef short s16x8 __attribute__((ext_vector_type(8)));
typedef short s16x4 __attribute__((ext_vector_type(4)));

#define CSTR 40   // C row stride in shorts (80 B: 16B-aligned, <=2-way banks)

__device__ __forceinline__ short f2bf(float f) {
    unsigned u = __builtin_bit_cast(unsigned, f);
    unsigned r = (u + 0x7fffu + ((u >> 16) & 1u)) >> 16;   // RNE to bf16
    return (short)r;
}

__device__ __forceinline__ float max4(float4 v) {
    return fmaxf(fmaxf(v.x, v.y), fmaxf(v.z, v.w));
}

__device__ __forceinline__ void load_afrag(const float* __restrict__ trans,
                                           int row, int kg, s16x8* a)
{
#pragma unroll
    for (int j = 0; j < 8; ++j)
        (*a)[j] = f2bf(__expf(trans[row * 32 + kg * 8 + j]));
}

// One wave reduces NC0 f32 rows -> one f32 output row (log2(NC0) levels).
// C/M are wave-private LDS. em node at step s: (inW>>s)-1 + sid*(NC0>>s) + p.
// `active`: wave does compute; barriers are uniform across the block.
template <int NC0>
__device__ __forceinline__ void wave_reduce(
    bool active, int lane,
    const float* rows, const float* __restrict__ em, int inW, int sid,
    s16x8 a0, s16x8 a1, short* C, float* M, float* outrow)
{
    constexpr int STEPS = (NC0 == 32) ? 5 : 2;
    if (active) {
        int q = lane & 31, h = lane >> 5;
        if (q < NC0) {
            const float4* src = (const float4*)(rows + q * 32 + h * 16);
            float4 x0 = src[0], x1 = src[1], x2 = src[2], x3 = src[3];
            float mm = fmaxf(fmaxf(max4(x0), max4(x1)),
                             fmaxf(max4(x2), max4(x3)));
            mm = fmaxf(mm, __shfl_xor(mm, 32));   // combine the two halves
            s16x8 w0, w1;
            w0[0] = f2bf(__expf(x0.x - mm)); w0[1] = f2bf(__expf(x0.y - mm));
            w0[2] = f2bf(__expf(x0.z - mm)); w0[3] = f2bf(__expf(x0.w - mm));
            w0[4] = f2bf(__expf(x1.x - mm)); w0[5] = f2bf(__expf(x1.y - mm));
            w0[6] = f2bf(__expf(x1.z - mm)); w0[7] = f2bf(__expf(x1.w - mm));
            w1[0] = f2bf(__expf(x2.x - mm)); w1[1] = f2bf(__expf(x2.y - mm));
            w1[2] = f2bf(__expf(x2.z - mm)); w1[3] = f2bf(__expf(x2.w - mm));
            w1[4] = f2bf(__expf(x3.x - mm)); w1[5] = f2bf(__expf(x3.y - mm));
            w1[6] = f2bf(__expf(x3.z - mm)); w1[7] = f2bf(__expf(x3.w - mm));
            *(s16x8*)(C + q * CSTR + h * 16) = w0;
            *(s16x8*)(C + q * CSTR + h * 16 + 8) = w1;
            if (h == 0) M[q] = mm;
        }
    }
    __syncthreads();
    const int ql = lane & 15, kg = lane >> 4;
    int nc = NC0;
#pragma unroll
    for (int s = 1; s <= STEPS; ++s) {
        const int Wp = inW >> s;
        const int nstr = (nc + 15) >> 4;
        for (int st = 0; st < nstr; ++st) {
            if (active) {
                int q = st * 16 + ql;
                bool valid = q < nc;
                s16x8 b = *(const s16x8*)(C + q * CSTR + kg * 8);
                f32x4 d0 = {0.f, 0.f, 0.f, 0.f};
                f32x4 d1 = {0.f, 0.f, 0.f, 0.f};
                d0 = __builtin_amdgcn_mfma_f32_16x16x32_bf16(a0, b, d0, 0, 0, 0);
                d1 = __builtin_amdgcn_mfma_f32_16x16x32_bf16(a1, b, d1, 0, 0, 0);
                float mq = M[q];
                int p = q >> 1;
                size_t node = (size_t)(Wp - 1) + (size_t)sid * (NC0 >> s) + p;
                float4 e0 = *((const float4*)(em + node * 32 + kg * 4));
                float4 e1 = *((const float4*)(em + node * 32 + 16 + kg * 4));
                float v0[4], v1[4];
#pragma unroll
                for (int r = 0; r < 4; ++r) {
                    float t0 = mq + __logf(d0[r]);
                    float t1 = mq + __logf(d1[r]);
                    v0[r] = t0 + __shfl_xor(t0, 1);   // + sibling child q^1
                    v1[r] = t1 + __shfl_xor(t1, 1);
                }
                v0[0] += e0.x; v0[1] += e0.y; v0[2] += e0.z; v0[3] += e0.w;
                v1[0] += e1.x; v1[1] += e1.y; v1[2] += e1.z; v1[3] += e1.w;
                if (s == STEPS) {
                    if (ql == 0) {                    // single parent row out
                        float4 o0 = {v0[0], v0[1], v0[2], v0[3]};
                        float4 o1 = {v1[0], v1[1], v1[2], v1[3]};
                        *(float4*)(outrow + kg * 4) = o0;
                        *(float4*)(outrow + 16 + kg * 4) = o1;
                    }
                } else {
                    float m2 = fmaxf(
                        fmaxf(fmaxf(v0[0], v0[1]), fmaxf(v0[2], v0[3])),
                        fmaxf(fmaxf(v1[0], v1[1]), fmaxf(v1[2], v1[3])));
                    m2 = fmaxf(m2, __shfl_xor(m2, 16));
                    m2 = fmaxf(m2, __shfl_xor(m2, 32)); // max over 32 channels
                    if (valid && !(q & 1)) {
                        s16x4 u0, u1;
                        u0[0] = f2bf(__expf(v0[0] - m2));
                        u0[1] = f2bf(__expf(v0[1] - m2));
                        u0[2] = f2bf(__expf(v0[2] - m2));
                        u0[3] = f2bf(__expf(v0[3] - m2));
                        u1[0] = f2bf(__expf(v1[0] - m2));
                        u1[1] = f2bf(__expf(v1[1] - m2));
                        u1[2] = f2bf(__expf(v1[2] - m2));
                        u1[3] = f2bf(__expf(v1[3] - m2));
                        *(s16x4*)(C + p * CSTR + kg * 4) = u0;
                        *(s16x4*)(C + p * CSTR + 16 + kg * 4) = u1;
                        if (kg == 0) M[p] = m2;
                    }
                }
            }
        }
        __syncthreads();
        nc >>= 1;
    }
}

// Generic stage: 4 waves/block, wave wv reduces rows_base[sid*32 .. +32) -> out[sid].
__global__ __launch_bounds__(256) void treecrf_stage(
    const float* __restrict__ rows_base, const float* __restrict__ em,
    const float* __restrict__ trans, float* __restrict__ out, int inW)
{
    __shared__ short C[4 * 32 * CSTR];
    __shared__ float M[4 * 32];
    int t = threadIdx.x, lane = t & 63, wv = t >> 6;
    int sid = blockIdx.x * 4 + wv;
    s16x8 a0, a1;
    load_afrag(trans, lane & 15, lane >> 4, &a0);
    load_afrag(trans, (lane & 15) + 16, lane >> 4, &a1);
    wave_reduce<32>(true, lane, rows_base + (size_t)sid * 1024, em, inW, sid,
                    a0, a1, C + wv * 32 * CSTR, M + wv * 32,
                    out + (size_t)sid * 32);
}

// Final: 4 waves do 128 -> 4 into LDS; wave 0 does 4 -> 1 -> root.
__global__ __launch_bounds__(256) void treecrf_final(
    const float* __restrict__ ws2, const float* __restrict__ em,
    const float* __restrict__ trans, float* __restrict__ out_root)
{
    __shared__ short C[4 * 32 * CSTR];
    __shared__ float M[4 * 32];
    __shared__ float R4[4 * 32];
    int t = threadIdx.x, lane = t & 63, wv = t >> 6;
    s16x8 a0, a1;
    load_afrag(trans, lane & 15, lane >> 4, &a0);
    load_afrag(trans, (lane & 15) + 16, lane >> 4, &a1);
    wave_reduce<32>(true, lane, ws2 + (size_t)wv * 1024, em, 128, wv,
                    a0, a1, C + wv * 32 * CSTR, M + wv * 32, R4 + wv * 32);
    __syncthreads();
    wave_reduce<4>(wv == 0, lane, R4, em, 4, 0, a0, a1, C, M, out_root);
}

extern "C" void kernel_launch(void* const* d_in, const int* in_sizes, int n_in,
                              void* d_out, int out_size, void* d_ws, size_t ws_size,
                              hipStream_t stream)
{
    const float* em = (const float*)d_in[0];
    const float* trans = (const float*)d_in[1];
    int n_nodes = in_sizes[0] / 32;          // 262143
    int n_leaves = (n_nodes + 1) / 2;        // 131072

    float* ws1 = (float*)d_ws;               // 4096 rows
    float* ws2 = ws1 + (size_t)4096 * 32;    // 128 rows

    // K1: leaves (width 131072) -> width 4096. 4096 waves = 1024 blocks.
    treecrf_stage<<<dim3(n_leaves / 128), dim3(256), 0, stream>>>(
        em + (size_t)(n_leaves - 1) * 32, em, trans, ws1, n_leaves);
    // K2: width 4096 -> width 128. 128 waves = 32 blocks.
    treecrf_stage<<<dim3(32), dim3(256), 0, stream>>>(
        ws1, em, trans, ws2, 4096);
    // K3: width 128 -> root.
    treecrf_final<<<dim3(1), dim3(256), 0, stream>>>(
        ws2, em, trans, (float*)d_out);
}

// Round 11
// 95.911 us; speedup vs baseline: 1.1437x; 1.0222x over previous
//
#include <hip/hip_runtime.h>

// TreeCRF inside pass, L=32 channels, perfect binary tree (heap layout).
// parent[i] = em[i] + LSE_j(T[i,j]+left[j]) + LSE_j(T[i,j]+right[j])
// LSE_j(T[i,j]+c[j]) = m + log(sum_j E[i,j]*exp(c[j]-m)), E=exp(T), m=max_j c[j].
//
// R11 = R10 (wave-autonomous subtrees + full em prefetch) with the correct
// intra-wave LDS ordering: R10 removed __syncthreads assuming program-order
// DS visibility; in fact lgkmcnt-tracked DS ops need an explicit wait when
// the write->read dependency crosses lanes (compiler can't prove aliasing).
// Fix: `s_waitcnt lgkmcnt(0)` + compiler memory barrier at each phase
// boundary — waits only this wave's DS queue (a few cycles), leaves the em
// prefetch (vmcnt) in flight, no s_barrier.
// K1: 4096 waves (131072 leaves -> 4096), K2: 128 waves (4096 -> 128),
// K3: 1 block (4 waves 128 -> 4 in LDS, real barrier, wave 0 does 4 -> 1).

typedef float f32x4 __attribute__((ext_vector_type(4)));
typedef short s16x8 __attribute__((ext_vector_type(8)));
typedef short s16x4 __attribute__((ext_vector_type(4)));

#define CSTR 40   // C row stride in shorts (80 B: 16B-aligned, <=2-way banks)
#define LDS_WAIT() __asm__ volatile("s_waitcnt lgkmcnt(0)" ::: "memory")

__device__ __forceinline__ short f2bf(float f) {
    unsigned u = __builtin_bit_cast(unsigned, f);
    unsigned r = (u + 0x7fffu + ((u >> 16) & 1u)) >> 16;   // RNE to bf16
    return (short)r;
}

__device__ __forceinline__ float max4(float4 v) {
    return fmaxf(fmaxf(v.x, v.y), fmaxf(v.z, v.w));
}

__device__ __forceinline__ void load_afrag(const float* __restrict__ trans,
                                           int row, int kg, s16x8* a)
{
#pragma unroll
    for (int j = 0; j < 8; ++j)
        (*a)[j] = f2bf(__expf(trans[row * 32 + kg * 8 + j]));
}

// One wave reduces NC0 rows -> one f32 output row (log2(NC0) levels), fully
// autonomously. em node at step s: (inW>>s)-1 + sid*(NC0>>s) + p.
template <int NC0>
__device__ __forceinline__ void wave_reduce(
    int lane, const float* rows, const float* __restrict__ em, int inW,
    int sid, s16x8 a0, s16x8 a1, short* C, float* M, float* outrow)
{
    constexpr int STEPS = (NC0 == 32) ? 5 : 2;
    constexpr int NPH = (NC0 == 32) ? 6 : 2;
    const int ql = lane & 15, kg = lane >> 4;
    const int q0 = lane & 31, h = lane >> 5;

    // stage-0 row loads first
    float4 x0 = {0,0,0,0}, x1 = x0, x2 = x0, x3 = x0;
    if (q0 < NC0) {
        const float4* src = (const float4*)(rows + q0 * 32 + h * 16);
        x0 = src[0]; x1 = src[1]; x2 = src[2]; x3 = src[3];
    }

    // prefetch ALL em rows needed by the phases (independent, in-flight)
    float4 pe0[NPH], pe1[NPH];
    {
        int ph = 0;
#pragma unroll
        for (int s = 1; s <= STEPS; ++s) {
            const int nca = NC0 >> (s - 1);
            const int nstr = (nca >= 16) ? (nca >> 4) : 1;
#pragma unroll
            for (int st = 0; st < nstr; ++st, ++ph) {
                int p = (st * 16 + ql) >> 1;
                size_t node = (size_t)((inW >> s) - 1)
                            + (size_t)sid * (NC0 >> s) + p;
                pe0[ph] = *(const float4*)(em + node * 32 + kg * 4);
                pe1[ph] = *(const float4*)(em + node * 32 + 16 + kg * 4);
            }
        }
    }

    // stage 0: exp rows -> C, maxes -> M
    if (q0 < NC0) {
        float mm = fmaxf(fmaxf(max4(x0), max4(x1)),
                         fmaxf(max4(x2), max4(x3)));
        mm = fmaxf(mm, __shfl_xor(mm, 32));       // combine the two halves
        s16x8 w0, w1;
        w0[0] = f2bf(__expf(x0.x - mm)); w0[1] = f2bf(__expf(x0.y - mm));
        w0[2] = f2bf(__expf(x0.z - mm)); w0[3] = f2bf(__expf(x0.w - mm));
        w0[4] = f2bf(__expf(x1.x - mm)); w0[5] = f2bf(__expf(x1.y - mm));
        w0[6] = f2bf(__expf(x1.z - mm)); w0[7] = f2bf(__expf(x1.w - mm));
        w1[0] = f2bf(__expf(x2.x - mm)); w1[1] = f2bf(__expf(x2.y - mm));
        w1[2] = f2bf(__expf(x2.z - mm)); w1[3] = f2bf(__expf(x2.w - mm));
        w1[4] = f2bf(__expf(x3.x - mm)); w1[5] = f2bf(__expf(x3.y - mm));
        w1[6] = f2bf(__expf(x3.z - mm)); w1[7] = f2bf(__expf(x3.w - mm));
        *(s16x8*)(C + q0 * CSTR + h * 16) = w0;
        *(s16x8*)(C + q0 * CSTR + h * 16 + 8) = w1;
        if (h == 0) M[q0] = mm;
    }

    int nc = NC0, ph = 0;
#pragma unroll
    for (int s = 1; s <= STEPS; ++s) {
        const int nstr = (nc >= 16) ? (nc >> 4) : 1;
#pragma unroll
        for (int st = 0; st < nstr; ++st, ++ph) {
            LDS_WAIT();   // drain this wave's DS writes; compiler mem barrier
            int q = st * 16 + ql;
            bool valid = q < nc;
            s16x8 b = *(const s16x8*)(C + q * CSTR + kg * 8);
            f32x4 d0 = {0.f, 0.f, 0.f, 0.f};
            f32x4 d1 = {0.f, 0.f, 0.f, 0.f};
            d0 = __builtin_amdgcn_mfma_f32_16x16x32_bf16(a0, b, d0, 0, 0, 0);
            d1 = __builtin_amdgcn_mfma_f32_16x16x32_bf16(a1, b, d1, 0, 0, 0);
            float mq = M[q];
            int p = q >> 1;
            float4 e0 = pe0[ph], e1 = pe1[ph];
            float v0[4], v1[4];
#pragma unroll
            for (int r = 0; r < 4; ++r) {
                float t0 = mq + __logf(d0[r]);
                float t1 = mq + __logf(d1[r]);
                v0[r] = t0 + __shfl_xor(t0, 1);   // + sibling child q^1
                v1[r] = t1 + __shfl_xor(t1, 1);
            }
            v0[0] += e0.x; v0[1] += e0.y; v0[2] += e0.z; v0[3] += e0.w;
            v1[0] += e1.x; v1[1] += e1.y; v1[2] += e1.z; v1[3] += e1.w;
            if (s == STEPS) {
                if (ql == 0) {                    // single parent row out
                    float4 o0 = {v0[0], v0[1], v0[2], v0[3]};
                    float4 o1 = {v1[0], v1[1], v1[2], v1[3]};
                    *(float4*)(outrow + kg * 4) = o0;
                    *(float4*)(outrow + 16 + kg * 4) = o1;
                }
            } else {
                float m2 = fmaxf(
                    fmaxf(fmaxf(v0[0], v0[1]), fmaxf(v0[2], v0[3])),
                    fmaxf(fmaxf(v1[0], v1[1]), fmaxf(v1[2], v1[3])));
                m2 = fmaxf(m2, __shfl_xor(m2, 16));
                m2 = fmaxf(m2, __shfl_xor(m2, 32));  // max over 32 channels
                if (valid && !(q & 1)) {
                    s16x4 u0, u1;
                    u0[0] = f2bf(__expf(v0[0] - m2));
                    u0[1] = f2bf(__expf(v0[1] - m2));
                    u0[2] = f2bf(__expf(v0[2] - m2));
                    u0[3] = f2bf(__expf(v0[3] - m2));
                    u1[0] = f2bf(__expf(v1[0] - m2));
                    u1[1] = f2bf(__expf(v1[1] - m2));
                    u1[2] = f2bf(__expf(v1[2] - m2));
                    u1[3] = f2bf(__expf(v1[3] - m2));
                    *(s16x4*)(C + p * CSTR + kg * 4) = u0;
                    *(s16x4*)(C + p * CSTR + 16 + kg * 4) = u1;
                    if (kg == 0) M[p] = m2;
                }
            }
        }
        nc >>= 1;
    }
}

// Generic stage: 4 waves/block, wave wv reduces rows_base[sid*32 .. +32) -> out[sid].
__global__ __launch_bounds__(256) void treecrf_stage(
    const float* __restrict__ rows_base, const float* __restrict__ em,
    const float* __restrict__ trans, float* __restrict__ out, int inW)
{
    __shared__ short C[4 * 32 * CSTR];
    __shared__ float M[4 * 32];
    int t = threadIdx.x, lane = t & 63, wv = t >> 6;
    int sid = blockIdx.x * 4 + wv;
    s16x8 a0, a1;
    load_afrag(trans, lane & 15, lane >> 4, &a0);
    load_afrag(trans, (lane & 15) + 16, lane >> 4, &a1);
    wave_reduce<32>(lane, rows_base + (size_t)sid * 1024, em, inW, sid,
                    a0, a1, C + wv * 32 * CSTR, M + wv * 32,
                    out + (size_t)sid * 32);
}

// Final: 4 waves do 128 -> 4 into LDS; barrier; wave 0 does 4 -> 1 -> root.
__global__ __launch_bounds__(256) void treecrf_final(
    const float* __restrict__ ws2, const float* __restrict__ em,
    const float* __restrict__ trans, float* __restrict__ out_root)
{
    __shared__ short C[4 * 32 * CSTR];
    __shared__ float M[4 * 32];
    __shared__ float R4[4 * 32];
    int t = threadIdx.x, lane = t & 63, wv = t >> 6;
    s16x8 a0, a1;
    load_afrag(trans, lane & 15, lane >> 4, &a0);
    load_afrag(trans, (lane & 15) + 16, lane >> 4, &a1);
    wave_reduce<32>(lane, ws2 + (size_t)wv * 1024, em, 128, wv,
                    a0, a1, C + wv * 32 * CSTR, M + wv * 32, R4 + wv * 32);
    __syncthreads();                       // cross-wave R4 handoff
    if (wv == 0)
        wave_reduce<4>(lane, R4, em, 4, 0, a0, a1, C, M, out_root);
}

extern "C" void kernel_launch(void* const* d_in, const int* in_sizes, int n_in,
                              void* d_out, int out_size, void* d_ws, size_t ws_size,
                              hipStream_t stream)
{
    const float* em = (const float*)d_in[0];
    const float* trans = (const float*)d_in[1];
    int n_nodes = in_sizes[0] / 32;          // 262143
    int n_leaves = (n_nodes + 1) / 2;        // 131072

    float* ws1 = (float*)d_ws;               // 4096 rows
    float* ws2 = ws1 + (size_t)4096 * 32;    // 128 rows

    // K1: leaves (width 131072) -> width 4096. 4096 waves = 1024 blocks.
    treecrf_stage<<<dim3(n_leaves / 128), dim3(256), 0, stream>>>(
        em + (size_t)(n_leaves - 1) * 32, em, trans, ws1, n_leaves);
    // K2: width 4096 -> width 128. 128 waves = 32 blocks.
    treecrf_stage<<<dim3(32), dim3(256), 0, stream>>>(
        ws1, em, trans, ws2, 4096);
    // K3: width 128 -> root.
    treecrf_final<<<dim3(1), dim3(256), 0, stream>>>(
        ws2, em, trans, (float*)d_out);
}

// Round 12
// 95.170 us; speedup vs baseline: 1.1526x; 1.0078x over previous
//
#include <hip/hip_runtime.h>

// TreeCRF inside pass, L=32 channels, perfect binary tree (heap layout).
// parent[i] = em[i] + LSE_j(T[i,j]+left[j]) + LSE_j(T[i,j]+right[j])
// LSE_j(T[i,j]+c[j]) = m + log(sum_j E[i,j]*exp(c[j]-m)), E=exp(T), m=max_j c[j].
//
// R12 = R11 (wave-autonomous 32-row subtrees, MFMA 16x16x32 bf16, full em
// prefetch, lgkmcnt-only intra-wave ordering) with the launch count cut to 2:
//  K1: 4096 waves reduce leaves -> width 4096 (block 0 also zeroes the ticket
//      counter; kernel boundary makes it visible to K2).
//  K2: 32 blocks x 4 waves reduce 4096 -> 128; threadfence + atomicAdd ticket;
//      the last block then runs the verified 128 -> 4 -> 1 path to the root
//      (R8's ticket primitive, R11's compute structure).

typedef float f32x4 __attribute__((ext_vector_type(4)));
typedef short s16x8 __attribute__((ext_vector_type(8)));
typedef short s16x4 __attribute__((ext_vector_type(4)));

#define CSTR 40   // C row stride in shorts (80 B: 16B-aligned, <=2-way banks)
#define LDS_WAIT() __asm__ volatile("s_waitcnt lgkmcnt(0)" ::: "memory")

__device__ __forceinline__ short f2bf(float f) {
    unsigned u = __builtin_bit_cast(unsigned, f);
    unsigned r = (u + 0x7fffu + ((u >> 16) & 1u)) >> 16;   // RNE to bf16
    return (short)r;
}

__device__ __forceinline__ float max4(float4 v) {
    return fmaxf(fmaxf(v.x, v.y), fmaxf(v.z, v.w));
}

__device__ __forceinline__ void load_afrag(const float* __restrict__ trans,
                                           int row, int kg, s16x8* a)
{
#pragma unroll
    for (int j = 0; j < 8; ++j)
        (*a)[j] = f2bf(__expf(trans[row * 32 + kg * 8 + j]));
}

// One wave reduces NC0 rows -> one f32 output row (log2(NC0) levels), fully
// autonomously. em node at step s: (inW>>s)-1 + sid*(NC0>>s) + p.
template <int NC0>
__device__ __forceinline__ void wave_reduce(
    int lane, const float* rows, const float* __restrict__ em, int inW,
    int sid, s16x8 a0, s16x8 a1, short* C, float* M, float* outrow)
{
    constexpr int STEPS = (NC0 == 32) ? 5 : 2;
    constexpr int NPH = (NC0 == 32) ? 6 : 2;
    const int ql = lane & 15, kg = lane >> 4;
    const int q0 = lane & 31, h = lane >> 5;

    // stage-0 row loads first
    float4 x0 = {0,0,0,0}, x1 = x0, x2 = x0, x3 = x0;
    if (q0 < NC0) {
        const float4* src = (const float4*)(rows + q0 * 32 + h * 16);
        x0 = src[0]; x1 = src[1]; x2 = src[2]; x3 = src[3];
    }

    // prefetch ALL em rows needed by the phases (independent, in-flight)
    float4 pe0[NPH], pe1[NPH];
    {
        int ph = 0;
#pragma unroll
        for (int s = 1; s <= STEPS; ++s) {
            const int nca = NC0 >> (s - 1);
            const int nstr = (nca >= 16) ? (nca >> 4) : 1;
#pragma unroll
            for (int st = 0; st < nstr; ++st, ++ph) {
                int p = (st * 16 + ql) >> 1;
                size_t node = (size_t)((inW >> s) - 1)
                            + (size_t)sid * (NC0 >> s) + p;
                pe0[ph] = *(const float4*)(em + node * 32 + kg * 4);
                pe1[ph] = *(const float4*)(em + node * 32 + 16 + kg * 4);
            }
        }
    }

    // stage 0: exp rows -> C, maxes -> M
    if (q0 < NC0) {
        float mm = fmaxf(fmaxf(max4(x0), max4(x1)),
                         fmaxf(max4(x2), max4(x3)));
        mm = fmaxf(mm, __shfl_xor(mm, 32));       // combine the two halves
        s16x8 w0, w1;
        w0[0] = f2bf(__expf(x0.x - mm)); w0[1] = f2bf(__expf(x0.y - mm));
        w0[2] = f2bf(__expf(x0.z - mm)); w0[3] = f2bf(__expf(x0.w - mm));
        w0[4] = f2bf(__expf(x1.x - mm)); w0[5] = f2bf(__expf(x1.y - mm));
        w0[6] = f2bf(__expf(x1.z - mm)); w0[7] = f2bf(__expf(x1.w - mm));
        w1[0] = f2bf(__expf(x2.x - mm)); w1[1] = f2bf(__expf(x2.y - mm));
        w1[2] = f2bf(__expf(x2.z - mm)); w1[3] = f2bf(__expf(x2.w - mm));
        w1[4] = f2bf(__expf(x3.x - mm)); w1[5] = f2bf(__expf(x3.y - mm));
        w1[6] = f2bf(__expf(x3.z - mm)); w1[7] = f2bf(__expf(x3.w - mm));
        *(s16x8*)(C + q0 * CSTR + h * 16) = w0;
        *(s16x8*)(C + q0 * CSTR + h * 16 + 8) = w1;
        if (h == 0) M[q0] = mm;
    }

    int nc = NC0, ph = 0;
#pragma unroll
    for (int s = 1; s <= STEPS; ++s) {
        const int nstr = (nc >= 16) ? (nc >> 4) : 1;
#pragma unroll
        for (int st = 0; st < nstr; ++st, ++ph) {
            LDS_WAIT();   // drain this wave's DS writes; compiler mem barrier
            int q = st * 16 + ql;
            bool valid = q < nc;
            s16x8 b = *(const s16x8*)(C + q * CSTR + kg * 8);
            f32x4 d0 = {0.f, 0.f, 0.f, 0.f};
            f32x4 d1 = {0.f, 0.f, 0.f, 0.f};
            d0 = __builtin_amdgcn_mfma_f32_16x16x32_bf16(a0, b, d0, 0, 0, 0);
            d1 = __builtin_amdgcn_mfma_f32_16x16x32_bf16(a1, b, d1, 0, 0, 0);
            float mq = M[q];
            int p = q >> 1;
            float4 e0 = pe0[ph], e1 = pe1[ph];
            float v0[4], v1[4];
#pragma unroll
            for (int r = 0; r < 4; ++r) {
                float t0 = mq + __logf(d0[r]);
                float t1 = mq + __logf(d1[r]);
                v0[r] = t0 + __shfl_xor(t0, 1);   // + sibling child q^1
                v1[r] = t1 + __shfl_xor(t1, 1);
            }
            v0[0] += e0.x; v0[1] += e0.y; v0[2] += e0.z; v0[3] += e0.w;
            v1[0] += e1.x; v1[1] += e1.y; v1[2] += e1.z; v1[3] += e1.w;
            if (s == STEPS) {
                if (ql == 0) {                    // single parent row out
                    float4 o0 = {v0[0], v0[1], v0[2], v0[3]};
                    float4 o1 = {v1[0], v1[1], v1[2], v1[3]};
                    *(float4*)(outrow + kg * 4) = o0;
                    *(float4*)(outrow + 16 + kg * 4) = o1;
                }
            } else {
                float m2 = fmaxf(
                    fmaxf(fmaxf(v0[0], v0[1]), fmaxf(v0[2], v0[3])),
                    fmaxf(fmaxf(v1[0], v1[1]), fmaxf(v1[2], v1[3])));
                m2 = fmaxf(m2, __shfl_xor(m2, 16));
                m2 = fmaxf(m2, __shfl_xor(m2, 32));  // max over 32 channels
                if (valid && !(q & 1)) {
                    s16x4 u0, u1;
                    u0[0] = f2bf(__expf(v0[0] - m2));
                    u0[1] = f2bf(__expf(v0[1] - m2));
                    u0[2] = f2bf(__expf(v0[2] - m2));
                    u0[3] = f2bf(__expf(v0[3] - m2));
                    u1[0] = f2bf(__expf(v1[0] - m2));
                    u1[1] = f2bf(__expf(v1[1] - m2));
                    u1[2] = f2bf(__expf(v1[2] - m2));
                    u1[3] = f2bf(__expf(v1[3] - m2));
                    *(s16x4*)(C + p * CSTR + kg * 4) = u0;
                    *(s16x4*)(C + p * CSTR + 16 + kg * 4) = u1;
                    if (kg == 0) M[p] = m2;
                }
            }
        }
        nc >>= 1;
    }
}

// K1: 4 waves/block, wave wv reduces 32 leaf rows -> out[sid]. Block 0 also
// zeroes the K2 ticket counter (visible to K2 at kernel boundary).
__global__ __launch_bounds__(256) void treecrf_stage1(
    const float* __restrict__ rows_base, const float* __restrict__ em,
    const float* __restrict__ trans, float* __restrict__ out, int inW,
    int* __restrict__ counter)
{
    __shared__ short C[4 * 32 * CSTR];
    __shared__ float M[4 * 32];
    int t = threadIdx.x, lane = t & 63, wv = t >> 6;
    if (blockIdx.x == 0 && t == 0) *counter = 0;
    int sid = blockIdx.x * 4 + wv;
    s16x8 a0, a1;
    load_afrag(trans, lane & 15, lane >> 4, &a0);
    load_afrag(trans, (lane & 15) + 16, lane >> 4, &a1);
    wave_reduce<32>(lane, rows_base + (size_t)sid * 1024, em, inW, sid,
                    a0, a1, C + wv * 32 * CSTR, M + wv * 32,
                    out + (size_t)sid * 32);
}

// K2: 32 blocks x 4 waves reduce 4096 -> 128 (ws2); ticket; last block runs
// 128 -> 4 (4 waves into LDS) -> barrier -> 4 -> 1 (wave 0) -> root.
__global__ __launch_bounds__(256) void treecrf_stage2(
    const float* __restrict__ ws1, float* __restrict__ ws2,
    const float* __restrict__ em, const float* __restrict__ trans,
    int* __restrict__ counter, float* __restrict__ out_root, int nbm1)
{
    __shared__ short C[4 * 32 * CSTR];
    __shared__ float M[4 * 32];
    __shared__ float R4[4 * 32];
    __shared__ int last_flag;
    int t = threadIdx.x, lane = t & 63, wv = t >> 6;
    int sid = blockIdx.x * 4 + wv;
    s16x8 a0, a1;
    load_afrag(trans, lane & 15, lane >> 4, &a0);
    load_afrag(trans, (lane & 15) + 16, lane >> 4, &a1);
    wave_reduce<32>(lane, ws1 + (size_t)sid * 1024, em, 4096, sid,
                    a0, a1, C + wv * 32 * CSTR, M + wv * 32,
                    ws2 + (size_t)sid * 32);

    if (t == 0) {
        __threadfence();                   // release this block's ws2 rows
        last_flag = (atomicAdd(counter, 1) == nbm1);
    }
    __syncthreads();
    if (!last_flag) return;
    __threadfence();                       // acquire all ws2 rows

    wave_reduce<32>(lane, ws2 + (size_t)wv * 1024, em, 128, wv,
                    a0, a1, C + wv * 32 * CSTR, M + wv * 32, R4 + wv * 32);
    __syncthreads();                       // cross-wave R4 handoff
    if (wv == 0)
        wave_reduce<4>(lane, R4, em, 4, 0, a0, a1, C, M, out_root);
}

extern "C" void kernel_launch(void* const* d_in, const int* in_sizes, int n_in,
                              void* d_out, int out_size, void* d_ws, size_t ws_size,
                              hipStream_t stream)
{
    const float* em = (const float*)d_in[0];
    const float* trans = (const float*)d_in[1];
    int n_nodes = in_sizes[0] / 32;          // 262143
    int n_leaves = (n_nodes + 1) / 2;        // 131072

    float* ws1 = (float*)d_ws;               // 4096 rows
    float* ws2 = ws1 + (size_t)4096 * 32;    // 128 rows
    int* counter = (int*)(ws2 + (size_t)128 * 32);

    // K1: leaves (width 131072) -> width 4096. 4096 waves = 1024 blocks.
    treecrf_stage1<<<dim3(n_leaves / 128), dim3(256), 0, stream>>>(
        em + (size_t)(n_leaves - 1) * 32, em, trans, ws1, n_leaves, counter);
    // K2: width 4096 -> root (last-block-done fuses the tail).
    treecrf_stage2<<<dim3(32), dim3(256), 0, stream>>>(
        ws1, ws2, em, trans, counter, (float*)d_out, 31);
}